// Round 1
// baseline (501.000 us; speedup 1.0000x reference)
//
#include <hip/hip_runtime.h>

// GNN: N=50000 nodes, E=800000 edges, IN=128, HID=64, OUT=128, EH=32, 3 etypes, 2 ntypes.
//
// Strategy:
//   feat @ eW[e] = nf[src] @ eW[e][:IN] + nf[dst] @ eW[e][IN:]
//   => precompute per-node projections P[n][192] (96 src-proj + 96 dst-proj, [e][o] layout),
//      then per-edge work is 32 adds + relu + register accumulation (gather over CSR-by-dst).
//   Node MLP: compute both node-type outputs as one GEMM [N,96]x[96,2*OUT], masked store.

// ---------------- CSR build (reused by both layers) ----------------

__global__ __launch_bounds__(256) void count_kernel(const int* __restrict__ dst,
                                                    int* __restrict__ deg, int E) {
  int i = blockIdx.x * 256 + threadIdx.x;
  if (i < E) atomicAdd(&deg[dst[i]], 1);
}

__global__ __launch_bounds__(1024) void scan_kernel(const int* __restrict__ deg,
                                                    int* __restrict__ rowstart, int n) {
  __shared__ int part[1024];
  int t = threadIdx.x;
  int chunk = (n + 1023) >> 10;
  int b = t * chunk;
  int e = min(n, b + chunk);
  int s = 0;
  for (int i = b; i < e; ++i) s += deg[i];
  part[t] = s;
  __syncthreads();
  for (int off = 1; off < 1024; off <<= 1) {
    int v = (t >= off) ? part[t - off] : 0;
    __syncthreads();
    part[t] += v;
    __syncthreads();
  }
  int run = part[t] - s;  // exclusive prefix
  for (int i = b; i < e; ++i) { rowstart[i] = run; run += deg[i]; }
  if (t == 1023) rowstart[n] = part[1023];
}

__global__ __launch_bounds__(256) void fill_kernel(const int* __restrict__ src,
                                                   const int* __restrict__ dst,
                                                   const int* __restrict__ etype,
                                                   const int* __restrict__ rowstart,
                                                   int* __restrict__ cursor,
                                                   int* __restrict__ edata, int E) {
  int i = blockIdx.x * 256 + threadIdx.x;
  if (i < E) {
    int d = dst[i];
    int pos = rowstart[d] + atomicAdd(&cursor[d], 1);
    edata[pos] = (etype[i] << 16) | src[i];  // src < 65536 OK (N=50000)
  }
}

// ---------------- node projection GEMM: P[N,192] = X[N,IN] @ W2[IN,192] ----------------
// W2[k][j]: j<96 -> src half (e=j/32, o=j%32, row k of eW[e]); j>=96 -> dst half (row IN+k).
// Tile: 64 nodes x 192 outputs, K-chunk 32. Thread: 8 nodes x 6 outputs (j = t32 + 32c).

template <int IN>
__global__ __launch_bounds__(256) void proj_kernel(const float* __restrict__ X,
                                                   const float* __restrict__ eW,
                                                   float* __restrict__ P, int n) {
  __shared__ float Xs[64 * 32];   // [node][k]  8 KB
  __shared__ float Ws[32 * 192];  // [k][j]    24 KB
  const int tx = threadIdx.x;
  const int t32 = tx & 31;
  const int nn0 = (tx >> 5) * 8;
  const int base = blockIdx.x * 64;
  float acc[8][6];
#pragma unroll
  for (int i = 0; i < 8; ++i)
#pragma unroll
    for (int c = 0; c < 6; ++c) acc[i][c] = 0.f;

  for (int k0 = 0; k0 < IN; k0 += 32) {
    // stage X tile (coalesced float4; rows contiguous in n)
    for (int id = tx; id < 512; id += 256) {
      int i = id >> 3, kk4 = (id & 7) * 4;
      int node = base + i;
      float4 v = make_float4(0.f, 0.f, 0.f, 0.f);
      if (node < n) v = *(const float4*)(X + (size_t)node * IN + k0 + kk4);
      *(float4*)(Xs + i * 32 + kk4) = v;
    }
    // stage W tile
    for (int id = tx; id < 1536; id += 256) {
      int kk = id / 48;
      int j = (id % 48) * 4;
      int half = (j >= 96) ? 1 : 0;
      int jj = j - half * 96;
      int e = jj >> 5, o = jj & 31;
      float4 v = *(const float4*)(eW + ((size_t)((e * 2 + half) * IN) + k0 + kk) * 32 + o);
      *(float4*)(Ws + kk * 192 + j) = v;
    }
    __syncthreads();
#pragma unroll 4
    for (int kk = 0; kk < 32; ++kk) {
      float xv[8], wv[6];
#pragma unroll
      for (int i = 0; i < 8; ++i) xv[i] = Xs[(nn0 + i) * 32 + kk];  // half-wave broadcast
#pragma unroll
      for (int c = 0; c < 6; ++c) wv[c] = Ws[kk * 192 + t32 + 32 * c];  // bank = t32, clean
#pragma unroll
      for (int i = 0; i < 8; ++i)
#pragma unroll
        for (int c = 0; c < 6; ++c) acc[i][c] = fmaf(xv[i], wv[c], acc[i][c]);
    }
    __syncthreads();
  }
#pragma unroll
  for (int i = 0; i < 8; ++i) {
    int node = base + nn0 + i;
    if (node < n) {
#pragma unroll
      for (int c = 0; c < 6; ++c) P[(size_t)node * 192 + t32 + 32 * c] = acc[i][c];
    }
  }
}

// ---------------- edge aggregation (gather over CSR) ----------------
// One wave per node; lane = slot*32 + o; 2 edges per iteration.
// m = relu(Psrc[src][et][o] + Pdst[node][et][o] + eb[et][o]); per-type mean.

__global__ __launch_bounds__(256) void aggregate_kernel(const float* __restrict__ P,
                                                        const int* __restrict__ rowstart,
                                                        const int* __restrict__ edata,
                                                        const float* __restrict__ eb,
                                                        float* __restrict__ h, int n) {
  int wid = (blockIdx.x * 256 + threadIdx.x) >> 6;
  if (wid >= n) return;
  int lane = threadIdx.x & 63;
  int o = lane & 31, slot = lane >> 5;
  const float* Pd = P + (size_t)wid * 192 + 96;
  float pdb0 = Pd[o] + eb[o];
  float pdb1 = Pd[32 + o] + eb[32 + o];
  float pdb2 = Pd[64 + o] + eb[64 + o];
  float a0 = 0.f, a1 = 0.f, a2 = 0.f;
  int c0 = 0, c1 = 0, c2 = 0;
  int s = rowstart[wid], e = rowstart[wid + 1];
  for (int i = s + slot; i < e; i += 2) {
    int pk = edata[i];  // broadcast within half-wave
    int srcn = pk & 0xFFFF;
    int et = pk >> 16;
    float v = P[(size_t)srcn * 192 + et * 32 + o];  // 128B coalesced per half-wave
    float pb = (et == 0) ? pdb0 : ((et == 1) ? pdb1 : pdb2);
    float m = fmaxf(v + pb, 0.f);
    a0 += (et == 0) ? m : 0.f;
    a1 += (et == 1) ? m : 0.f;
    a2 += (et == 2) ? m : 0.f;
    c0 += (et == 0);
    c1 += (et == 1);
    c2 += (et == 2);
  }
  a0 += __shfl_xor(a0, 32);
  a1 += __shfl_xor(a1, 32);
  a2 += __shfl_xor(a2, 32);
  c0 += __shfl_xor(c0, 32);
  c1 += __shfl_xor(c1, 32);
  c2 += __shfl_xor(c2, 32);
  if (slot == 0) {
    float* hn = h + (size_t)wid * 96;
    hn[o] = a0 / fmaxf((float)c0, 1.f);
    hn[32 + o] = a1 / fmaxf((float)c1, 1.f);
    hn[64 + o] = a2 / fmaxf((float)c2, 1.f);
  }
}

// ---------------- node MLP: out = relu(h @ nW[nt] + nb[nt]), both types as one GEMM ----------------
// C[N, 2*OUT] = h[N,96] @ Wcat[96, 2*OUT]; store only the nt-matching half per node.

template <int OUT>
__global__ __launch_bounds__(256) void mlp_kernel(const float* __restrict__ H,
                                                  const float* __restrict__ nW,
                                                  const float* __restrict__ nb,
                                                  const int* __restrict__ ntype,
                                                  float* __restrict__ out, int n) {
  constexpr int J = 2 * OUT;   // 128 or 256
  constexpr int CJ = J / 32;   // 4 or 8
  __shared__ float Xs[32 * 32];  // 32 nodes x 32 k
  __shared__ float Ws[32 * J];   // 16 or 32 KB
  const int tx = threadIdx.x;
  const int t32 = tx & 31;
  const int nn0 = (tx >> 5) * 4;
  const int base = blockIdx.x * 32;
  float acc[4][CJ];
#pragma unroll
  for (int i = 0; i < 4; ++i)
#pragma unroll
    for (int c = 0; c < CJ; ++c) acc[i][c] = 0.f;

  for (int k0 = 0; k0 < 96; k0 += 32) {
    {  // stage Xs: exactly one float4 per thread
      int i = tx >> 3, kk4 = (tx & 7) * 4;
      int node = base + i;
      float4 v = make_float4(0.f, 0.f, 0.f, 0.f);
      if (node < n) v = *(const float4*)(H + (size_t)node * 96 + k0 + kk4);
      *(float4*)(Xs + i * 32 + kk4) = v;
    }
    for (int id = tx; id < 32 * J / 4; id += 256) {
      int kk = id / (J / 4);
      int j = (id % (J / 4)) * 4;
      int t = (j >= OUT) ? 1 : 0;
      int o = j & (OUT - 1);
      float4 v = *(const float4*)(nW + ((size_t)t * 96 + k0 + kk) * OUT + o);
      *(float4*)(Ws + kk * J + j) = v;
    }
    __syncthreads();
#pragma unroll 4
    for (int kk = 0; kk < 32; ++kk) {
      float xv[4], wv[CJ];
#pragma unroll
      for (int i = 0; i < 4; ++i) xv[i] = Xs[(nn0 + i) * 32 + kk];
#pragma unroll
      for (int c = 0; c < CJ; ++c) wv[c] = Ws[kk * J + t32 + 32 * c];
#pragma unroll
      for (int i = 0; i < 4; ++i)
#pragma unroll
        for (int c = 0; c < CJ; ++c) acc[i][c] = fmaf(xv[i], wv[c], acc[i][c]);
    }
    __syncthreads();
  }
#pragma unroll
  for (int i = 0; i < 4; ++i) {
    int node = base + nn0 + i;
    if (node < n) {
      int nt = ntype[node];
#pragma unroll
      for (int c = 0; c < CJ; ++c) {
        int j = t32 + 32 * c;
        if (((j >= OUT) ? 1 : 0) == nt) {
          out[(size_t)node * OUT + (j & (OUT - 1))] = fmaxf(acc[i][c] + nb[j], 0.f);
        }
      }
    }
  }
}

// ---------------- launch ----------------

extern "C" void kernel_launch(void* const* d_in, const int* in_sizes, int n_in,
                              void* d_out, int out_size, void* d_ws, size_t ws_size,
                              hipStream_t stream) {
  const float* nf    = (const float*)d_in[0];
  const int*   eidx  = (const int*)d_in[1];
  const int*   etype = (const int*)d_in[2];
  const int*   ntype = (const int*)d_in[3];
  const float* eW0   = (const float*)d_in[4];
  const float* eb0   = (const float*)d_in[5];
  const float* nW0   = (const float*)d_in[6];
  const float* nb0   = (const float*)d_in[7];
  const float* eW1   = (const float*)d_in[8];
  const float* eb1   = (const float*)d_in[9];
  const float* nW1   = (const float*)d_in[10];
  const float* nb1   = (const float*)d_in[11];
  const int N = in_sizes[3];   // node_type count
  const int E = in_sizes[2];   // edge_type count
  const int* srcv = eidx;
  const int* dstv = eidx + E;

  // workspace layout (~74 MB)
  float* P   = (float*)d_ws;                 // N*192
  float* h96 = P + (size_t)N * 192;          // N*96
  float* h64 = h96 + (size_t)N * 96;         // N*64
  int* rowstart = (int*)(h64 + (size_t)N * 64);  // N+1
  int* cursor   = rowstart + (N + 1);            // N
  int* edata    = cursor + N;                    // E

  // CSR build (graph identical for both layers)
  hipMemsetAsync(cursor, 0, (size_t)N * sizeof(int), stream);
  count_kernel<<<(E + 255) / 256, 256, 0, stream>>>(dstv, cursor, E);
  scan_kernel<<<1, 1024, 0, stream>>>(cursor, rowstart, N);
  hipMemsetAsync(cursor, 0, (size_t)N * sizeof(int), stream);
  fill_kernel<<<(E + 255) / 256, 256, 0, stream>>>(srcv, dstv, etype, rowstart, cursor, edata, E);

  int pgrid = (N + 63) / 64;
  int agrid = (N + 3) / 4;
  int mgrid = (N + 31) / 32;

  // layer 0: 128 -> 64
  proj_kernel<128><<<pgrid, 256, 0, stream>>>(nf, eW0, P, N);
  aggregate_kernel<<<agrid, 256, 0, stream>>>(P, rowstart, edata, eb0, h96, N);
  mlp_kernel<64><<<mgrid, 256, 0, stream>>>(h96, nW0, nb0, ntype, h64, N);

  // layer 1: 64 -> 128
  proj_kernel<64><<<pgrid, 256, 0, stream>>>(h64, eW1, P, N);
  aggregate_kernel<<<agrid, 256, 0, stream>>>(P, rowstart, edata, eb1, h96, N);
  mlp_kernel<128><<<mgrid, 256, 0, stream>>>(h96, nW1, nb1, ntype, (float*)d_out, N);
}

// Round 2
// 446.300 us; speedup vs baseline: 1.1226x; 1.1226x over previous
//
#include <hip/hip_runtime.h>

// GNN: N=50000 nodes, E=800000 edges, IN=128, HID=64, OUT=128, EH=32, 3 etypes, 2 ntypes.
//
// Strategy:
//   feat @ eW[e] = nf[src] @ eW[e][:IN] + nf[dst] @ eW[e][IN:]
//   => precompute per-node projections P[n][192] (96 src-proj + 96 dst-proj, [e][o] layout),
//      then per-edge work is 32 adds + relu + register accumulation (gather over CSR-by-dst).
//   Node MLP: compute both node-type outputs as one GEMM [N,96]x[96,2*OUT], masked store.
//
// R1: replaced single-block scan (77 us, 0.15% occupancy — latency-bound) with
//     3-kernel multi-block scan; fill_kernel now gets absolute positions from
//     cursor (= scanned rowstart copy), dropping one memset + one read/edge.

// ---------------- CSR build (reused by both layers) ----------------

__global__ __launch_bounds__(256) void count_kernel(const int* __restrict__ dst,
                                                    int* __restrict__ deg, int E) {
  int i = blockIdx.x * 256 + threadIdx.x;
  if (i < E) atomicAdd(&deg[dst[i]], 1);
}

// block-local exclusive scan: 256 threads x 4 elems = 1024 elems per block
__global__ __launch_bounds__(256) void scan1_kernel(const int* __restrict__ deg,
                                                    int* __restrict__ rowstart,
                                                    int* __restrict__ bsum, int n) {
  __shared__ int tmp[256];
  int t = threadIdx.x;
  int base = blockIdx.x * 1024 + t * 4;
  int v0 = 0, v1 = 0, v2 = 0, v3 = 0;
  if (base + 3 < n) {
    int4 d = *(const int4*)(deg + base);
    v0 = d.x; v1 = d.y; v2 = d.z; v3 = d.w;
  } else {
    if (base < n)     v0 = deg[base];
    if (base + 1 < n) v1 = deg[base + 1];
    if (base + 2 < n) v2 = deg[base + 2];
  }
  int s = v0 + v1 + v2 + v3;
  tmp[t] = s;
  __syncthreads();
  for (int off = 1; off < 256; off <<= 1) {
    int u = (t >= off) ? tmp[t - off] : 0;
    __syncthreads();
    tmp[t] += u;
    __syncthreads();
  }
  int excl = tmp[t] - s;
  if (base < n)     rowstart[base]     = excl;
  if (base + 1 < n) rowstart[base + 1] = excl + v0;
  if (base + 2 < n) rowstart[base + 2] = excl + v0 + v1;
  if (base + 3 < n) rowstart[base + 3] = excl + v0 + v1 + v2;
  if (t == 255) bsum[blockIdx.x] = tmp[255];
}

// scan of <=64 block sums in one wave; also writes rowstart[n] = total
__global__ __launch_bounds__(64) void scan2_kernel(const int* __restrict__ bsum,
                                                   int* __restrict__ boff, int nb,
                                                   int* __restrict__ rowstart, int n) {
  int lane = threadIdx.x;
  int v = (lane < nb) ? bsum[lane] : 0;
  int incl = v;
  for (int off = 1; off < 64; off <<= 1) {
    int u = __shfl_up(incl, off, 64);
    if (lane >= off) incl += u;
  }
  if (lane < nb) boff[lane] = incl - v;
  if (lane == 63) rowstart[n] = incl;
}

// apply block offsets; also materialize cursor = rowstart copy for fill
__global__ __launch_bounds__(256) void scan3_kernel(int* __restrict__ rowstart,
                                                    int* __restrict__ cursor,
                                                    const int* __restrict__ boff, int n) {
  int i = blockIdx.x * 256 + threadIdx.x;
  if (i < n) {
    int v = rowstart[i] + boff[i >> 10];
    rowstart[i] = v;
    cursor[i] = v;
  }
}

__global__ __launch_bounds__(256) void fill_kernel(const int* __restrict__ src,
                                                   const int* __restrict__ dst,
                                                   const int* __restrict__ etype,
                                                   int* __restrict__ cursor,
                                                   int* __restrict__ edata, int E) {
  int i = blockIdx.x * 256 + threadIdx.x;
  if (i < E) {
    int pos = atomicAdd(&cursor[dst[i]], 1);  // absolute position (cursor pre-seeded)
    edata[pos] = (etype[i] << 16) | src[i];   // src < 65536 OK (N=50000)
  }
}

// ---------------- node projection GEMM: P[N,192] = X[N,IN] @ W2[IN,192] ----------------
// W2[k][j]: j<96 -> src half (e=j/32, o=j%32, row k of eW[e]); j>=96 -> dst half (row IN+k).
// Tile: 64 nodes x 192 outputs, K-chunk 32. Thread: 8 nodes x 6 outputs (j = t32 + 32c).

template <int IN>
__global__ __launch_bounds__(256) void proj_kernel(const float* __restrict__ X,
                                                   const float* __restrict__ eW,
                                                   float* __restrict__ P, int n) {
  __shared__ float Xs[64 * 32];   // [node][k]  8 KB
  __shared__ float Ws[32 * 192];  // [k][j]    24 KB
  const int tx = threadIdx.x;
  const int t32 = tx & 31;
  const int nn0 = (tx >> 5) * 8;
  const int base = blockIdx.x * 64;
  float acc[8][6];
#pragma unroll
  for (int i = 0; i < 8; ++i)
#pragma unroll
    for (int c = 0; c < 6; ++c) acc[i][c] = 0.f;

  for (int k0 = 0; k0 < IN; k0 += 32) {
    // stage X tile (coalesced float4; rows contiguous in n)
    for (int id = tx; id < 512; id += 256) {
      int i = id >> 3, kk4 = (id & 7) * 4;
      int node = base + i;
      float4 v = make_float4(0.f, 0.f, 0.f, 0.f);
      if (node < n) v = *(const float4*)(X + (size_t)node * IN + k0 + kk4);
      *(float4*)(Xs + i * 32 + kk4) = v;
    }
    // stage W tile
    for (int id = tx; id < 1536; id += 256) {
      int kk = id / 48;
      int j = (id % 48) * 4;
      int half = (j >= 96) ? 1 : 0;
      int jj = j - half * 96;
      int e = jj >> 5, o = jj & 31;
      float4 v = *(const float4*)(eW + ((size_t)((e * 2 + half) * IN) + k0 + kk) * 32 + o);
      *(float4*)(Ws + kk * 192 + j) = v;
    }
    __syncthreads();
#pragma unroll 4
    for (int kk = 0; kk < 32; ++kk) {
      float xv[8], wv[6];
#pragma unroll
      for (int i = 0; i < 8; ++i) xv[i] = Xs[(nn0 + i) * 32 + kk];  // half-wave broadcast
#pragma unroll
      for (int c = 0; c < 6; ++c) wv[c] = Ws[kk * 192 + t32 + 32 * c];  // bank = t32, clean
#pragma unroll
      for (int i = 0; i < 8; ++i)
#pragma unroll
        for (int c = 0; c < 6; ++c) acc[i][c] = fmaf(xv[i], wv[c], acc[i][c]);
    }
    __syncthreads();
  }
#pragma unroll
  for (int i = 0; i < 8; ++i) {
    int node = base + nn0 + i;
    if (node < n) {
#pragma unroll
      for (int c = 0; c < 6; ++c) P[(size_t)node * 192 + t32 + 32 * c] = acc[i][c];
    }
  }
}

// ---------------- edge aggregation (gather over CSR) ----------------
// One wave per node; lane = slot*32 + o; 2 edges per iteration.
// m = relu(Psrc[src][et][o] + Pdst[node][et][o] + eb[et][o]); per-type mean.

__global__ __launch_bounds__(256) void aggregate_kernel(const float* __restrict__ P,
                                                        const int* __restrict__ rowstart,
                                                        const int* __restrict__ edata,
                                                        const float* __restrict__ eb,
                                                        float* __restrict__ h, int n) {
  int wid = (blockIdx.x * 256 + threadIdx.x) >> 6;
  if (wid >= n) return;
  int lane = threadIdx.x & 63;
  int o = lane & 31, slot = lane >> 5;
  const float* Pd = P + (size_t)wid * 192 + 96;
  float pdb0 = Pd[o] + eb[o];
  float pdb1 = Pd[32 + o] + eb[32 + o];
  float pdb2 = Pd[64 + o] + eb[64 + o];
  float a0 = 0.f, a1 = 0.f, a2 = 0.f;
  int c0 = 0, c1 = 0, c2 = 0;
  int s = rowstart[wid], e = rowstart[wid + 1];
  for (int i = s + slot; i < e; i += 2) {
    int pk = edata[i];  // broadcast within half-wave
    int srcn = pk & 0xFFFF;
    int et = pk >> 16;
    float v = P[(size_t)srcn * 192 + et * 32 + o];  // 128B coalesced per half-wave
    float pb = (et == 0) ? pdb0 : ((et == 1) ? pdb1 : pdb2);
    float m = fmaxf(v + pb, 0.f);
    a0 += (et == 0) ? m : 0.f;
    a1 += (et == 1) ? m : 0.f;
    a2 += (et == 2) ? m : 0.f;
    c0 += (et == 0);
    c1 += (et == 1);
    c2 += (et == 2);
  }
  a0 += __shfl_xor(a0, 32);
  a1 += __shfl_xor(a1, 32);
  a2 += __shfl_xor(a2, 32);
  c0 += __shfl_xor(c0, 32);
  c1 += __shfl_xor(c1, 32);
  c2 += __shfl_xor(c2, 32);
  if (slot == 0) {
    float* hn = h + (size_t)wid * 96;
    hn[o] = a0 / fmaxf((float)c0, 1.f);
    hn[32 + o] = a1 / fmaxf((float)c1, 1.f);
    hn[64 + o] = a2 / fmaxf((float)c2, 1.f);
  }
}

// ---------------- node MLP: out = relu(h @ nW[nt] + nb[nt]), both types as one GEMM ----------------
// C[N, 2*OUT] = h[N,96] @ Wcat[96, 2*OUT]; store only the nt-matching half per node.

template <int OUT>
__global__ __launch_bounds__(256) void mlp_kernel(const float* __restrict__ H,
                                                  const float* __restrict__ nW,
                                                  const float* __restrict__ nb,
                                                  const int* __restrict__ ntype,
                                                  float* __restrict__ out, int n) {
  constexpr int J = 2 * OUT;   // 128 or 256
  constexpr int CJ = J / 32;   // 4 or 8
  __shared__ float Xs[32 * 32];  // 32 nodes x 32 k
  __shared__ float Ws[32 * J];   // 16 or 32 KB
  const int tx = threadIdx.x;
  const int t32 = tx & 31;
  const int nn0 = (tx >> 5) * 4;
  const int base = blockIdx.x * 32;
  float acc[4][CJ];
#pragma unroll
  for (int i = 0; i < 4; ++i)
#pragma unroll
    for (int c = 0; c < CJ; ++c) acc[i][c] = 0.f;

  for (int k0 = 0; k0 < 96; k0 += 32) {
    {  // stage Xs: exactly one float4 per thread
      int i = tx >> 3, kk4 = (tx & 7) * 4;
      int node = base + i;
      float4 v = make_float4(0.f, 0.f, 0.f, 0.f);
      if (node < n) v = *(const float4*)(H + (size_t)node * 96 + k0 + kk4);
      *(float4*)(Xs + i * 32 + kk4) = v;
    }
    for (int id = tx; id < 32 * J / 4; id += 256) {
      int kk = id / (J / 4);
      int j = (id % (J / 4)) * 4;
      int t = (j >= OUT) ? 1 : 0;
      int o = j & (OUT - 1);
      float4 v = *(const float4*)(nW + ((size_t)t * 96 + k0 + kk) * OUT + o);
      *(float4*)(Ws + kk * J + j) = v;
    }
    __syncthreads();
#pragma unroll 4
    for (int kk = 0; kk < 32; ++kk) {
      float xv[4], wv[CJ];
#pragma unroll
      for (int i = 0; i < 4; ++i) xv[i] = Xs[(nn0 + i) * 32 + kk];
#pragma unroll
      for (int c = 0; c < CJ; ++c) wv[c] = Ws[kk * J + t32 + 32 * c];
#pragma unroll
      for (int i = 0; i < 4; ++i)
#pragma unroll
        for (int c = 0; c < CJ; ++c) acc[i][c] = fmaf(xv[i], wv[c], acc[i][c]);
    }
    __syncthreads();
  }
#pragma unroll
  for (int i = 0; i < 4; ++i) {
    int node = base + nn0 + i;
    if (node < n) {
      int nt = ntype[node];
#pragma unroll
      for (int c = 0; c < CJ; ++c) {
        int j = t32 + 32 * c;
        if (((j >= OUT) ? 1 : 0) == nt) {
          out[(size_t)node * OUT + (j & (OUT - 1))] = fmaxf(acc[i][c] + nb[j], 0.f);
        }
      }
    }
  }
}

// ---------------- launch ----------------

extern "C" void kernel_launch(void* const* d_in, const int* in_sizes, int n_in,
                              void* d_out, int out_size, void* d_ws, size_t ws_size,
                              hipStream_t stream) {
  const float* nf    = (const float*)d_in[0];
  const int*   eidx  = (const int*)d_in[1];
  const int*   etype = (const int*)d_in[2];
  const int*   ntype = (const int*)d_in[3];
  const float* eW0   = (const float*)d_in[4];
  const float* eb0   = (const float*)d_in[5];
  const float* nW0   = (const float*)d_in[6];
  const float* nb0   = (const float*)d_in[7];
  const float* eW1   = (const float*)d_in[8];
  const float* eb1   = (const float*)d_in[9];
  const float* nW1   = (const float*)d_in[10];
  const float* nb1   = (const float*)d_in[11];
  const int N = in_sizes[3];   // node_type count
  const int E = in_sizes[2];   // edge_type count
  const int* srcv = eidx;
  const int* dstv = eidx + E;

  // workspace layout (~74 MB)
  float* P   = (float*)d_ws;                 // N*192
  float* h96 = P + (size_t)N * 192;          // N*96
  float* h64 = h96 + (size_t)N * 96;         // N*64
  int* rowstart = (int*)(h64 + (size_t)N * 64);  // N+1
  int* cursor   = rowstart + (N + 1);            // N (aliases deg)
  int* bsum     = cursor + N;                    // 64
  int* boff     = bsum + 64;                     // 64
  int* edata    = boff + 64;                     // E

  const int nsb = (N + 1023) / 1024;  // scan blocks (<=64 for N<=65536)

  // CSR build (graph identical for both layers)
  hipMemsetAsync(cursor, 0, (size_t)N * sizeof(int), stream);
  count_kernel<<<(E + 255) / 256, 256, 0, stream>>>(dstv, cursor, E);
  scan1_kernel<<<nsb, 256, 0, stream>>>(cursor, rowstart, bsum, N);
  scan2_kernel<<<1, 64, 0, stream>>>(bsum, boff, nsb, rowstart, N);
  scan3_kernel<<<(N + 255) / 256, 256, 0, stream>>>(rowstart, cursor, boff, N);
  fill_kernel<<<(E + 255) / 256, 256, 0, stream>>>(srcv, dstv, etype, cursor, edata, E);

  int pgrid = (N + 63) / 64;
  int agrid = (N + 3) / 4;
  int mgrid = (N + 31) / 32;

  // layer 0: 128 -> 64
  proj_kernel<128><<<pgrid, 256, 0, stream>>>(nf, eW0, P, N);
  aggregate_kernel<<<agrid, 256, 0, stream>>>(P, rowstart, edata, eb0, h96, N);
  mlp_kernel<64><<<mgrid, 256, 0, stream>>>(h96, nW0, nb0, ntype, h64, N);

  // layer 1: 64 -> 128
  proj_kernel<64><<<pgrid, 256, 0, stream>>>(h64, eW1, P, N);
  aggregate_kernel<<<agrid, 256, 0, stream>>>(P, rowstart, edata, eb1, h96, N);
  mlp_kernel<128><<<mgrid, 256, 0, stream>>>(h96, nW1, nb1, ntype, (float*)d_out, N);
}

// Round 3
// 437.199 us; speedup vs baseline: 1.1459x; 1.0208x over previous
//
#include <hip/hip_runtime.h>

// GNN: N=50000 nodes, E=800000 edges, IN=128, HID=64, OUT=128, EH=32, 3 etypes, 2 ntypes.
//
// Strategy:
//   feat @ eW[e] = nf[src] @ eW[e][:IN] + nf[dst] @ eW[e][IN:]
//   => precompute per-node projections P[n][192] (96 src-proj + 96 dst-proj, [e][o] layout),
//      then per-edge work is 32 adds + relu + register accumulation (gather over CSR-by-dst).
//
// R1: multi-block scan (was 77 us single-block, 0.15% occupancy).
// R2: node MLP restructured — nodes partitioned by type (no 2x wasted compute),
//     LDS inner loop vectorized to ds_read_b128 (was 12 scalar b32 per kk ->
//     LDS-pipe-bound at 50% VALUBusy).

// ---------------- CSR build (reused by both layers) ----------------

__global__ __launch_bounds__(256) void count_kernel(const int* __restrict__ dst,
                                                    int* __restrict__ deg, int E) {
  int i = blockIdx.x * 256 + threadIdx.x;
  if (i < E) atomicAdd(&deg[dst[i]], 1);
}

// block-local exclusive scan: 256 threads x 4 elems = 1024 elems per block
__global__ __launch_bounds__(256) void scan1_kernel(const int* __restrict__ deg,
                                                    int* __restrict__ rowstart,
                                                    int* __restrict__ bsum, int n) {
  __shared__ int tmp[256];
  int t = threadIdx.x;
  int base = blockIdx.x * 1024 + t * 4;
  int v0 = 0, v1 = 0, v2 = 0, v3 = 0;
  if (base + 3 < n) {
    int4 d = *(const int4*)(deg + base);
    v0 = d.x; v1 = d.y; v2 = d.z; v3 = d.w;
  } else {
    if (base < n)     v0 = deg[base];
    if (base + 1 < n) v1 = deg[base + 1];
    if (base + 2 < n) v2 = deg[base + 2];
  }
  int s = v0 + v1 + v2 + v3;
  tmp[t] = s;
  __syncthreads();
  for (int off = 1; off < 256; off <<= 1) {
    int u = (t >= off) ? tmp[t - off] : 0;
    __syncthreads();
    tmp[t] += u;
    __syncthreads();
  }
  int excl = tmp[t] - s;
  if (base < n)     rowstart[base]     = excl;
  if (base + 1 < n) rowstart[base + 1] = excl + v0;
  if (base + 2 < n) rowstart[base + 2] = excl + v0 + v1;
  if (base + 3 < n) rowstart[base + 3] = excl + v0 + v1 + v2;
  if (t == 255) bsum[blockIdx.x] = tmp[255];
}

// scan of <=64 block sums in one wave; also writes rowstart[n] = total
__global__ __launch_bounds__(64) void scan2_kernel(const int* __restrict__ bsum,
                                                   int* __restrict__ boff, int nb,
                                                   int* __restrict__ rowstart, int n) {
  int lane = threadIdx.x;
  int v = (lane < nb) ? bsum[lane] : 0;
  int incl = v;
  for (int off = 1; off < 64; off <<= 1) {
    int u = __shfl_up(incl, off, 64);
    if (lane >= off) incl += u;
  }
  if (lane < nb) boff[lane] = incl - v;
  if (lane == 63) rowstart[n] = incl;
}

// apply block offsets; also materialize cursor = rowstart copy for fill
__global__ __launch_bounds__(256) void scan3_kernel(int* __restrict__ rowstart,
                                                    int* __restrict__ cursor,
                                                    const int* __restrict__ boff, int n) {
  int i = blockIdx.x * 256 + threadIdx.x;
  if (i < n) {
    int v = rowstart[i] + boff[i >> 10];
    rowstart[i] = v;
    cursor[i] = v;
  }
}

__global__ __launch_bounds__(256) void fill_kernel(const int* __restrict__ src,
                                                   const int* __restrict__ dst,
                                                   const int* __restrict__ etype,
                                                   int* __restrict__ cursor,
                                                   int* __restrict__ edata, int E) {
  int i = blockIdx.x * 256 + threadIdx.x;
  if (i < E) {
    int pos = atomicAdd(&cursor[dst[i]], 1);  // absolute position (cursor pre-seeded)
    edata[pos] = (etype[i] << 16) | src[i];   // src < 65536 OK (N=50000)
  }
}

// ---------------- node partition by type (unordered index lists) ----------------

__global__ __launch_bounds__(256) void partition_kernel(const int* __restrict__ ntype,
                                                        int* __restrict__ idxbuf,
                                                        int* __restrict__ tcnt,
                                                        int n, int ncap) {
  int i = blockIdx.x * 256 + threadIdx.x;
  int lane = threadIdx.x & 63;
  int t = (i < n) ? ntype[i] : -1;
  unsigned long long m0 = __ballot(t == 0);
  unsigned long long m1 = __ballot(t == 1);
  int b0 = 0, b1 = 0;
  if (lane == 0) {
    b0 = atomicAdd(&tcnt[0], (int)__popcll(m0));
    b1 = atomicAdd(&tcnt[1], (int)__popcll(m1));
  }
  b0 = __shfl(b0, 0);
  b1 = __shfl(b1, 0);
  unsigned long long below = (1ull << lane) - 1ull;
  if (t == 0) idxbuf[b0 + (int)__popcll(m0 & below)] = i;
  else if (t == 1) idxbuf[ncap + b1 + (int)__popcll(m1 & below)] = i;
}

// ---------------- node projection GEMM: P[N,192] = X[N,IN] @ W2[IN,192] ----------------
// W2[k][j]: j<96 -> src half (e=j/32, o=j%32, row k of eW[e]); j>=96 -> dst half (row IN+k).
// Tile: 64 nodes x 192 outputs, K-chunk 32. Thread: 8 nodes x 6 outputs (j = t32 + 32c).

template <int IN>
__global__ __launch_bounds__(256) void proj_kernel(const float* __restrict__ X,
                                                   const float* __restrict__ eW,
                                                   float* __restrict__ P, int n) {
  __shared__ float Xs[64 * 32];   // [node][k]  8 KB
  __shared__ float Ws[32 * 192];  // [k][j]    24 KB
  const int tx = threadIdx.x;
  const int t32 = tx & 31;
  const int nn0 = (tx >> 5) * 8;
  const int base = blockIdx.x * 64;
  float acc[8][6];
#pragma unroll
  for (int i = 0; i < 8; ++i)
#pragma unroll
    for (int c = 0; c < 6; ++c) acc[i][c] = 0.f;

  for (int k0 = 0; k0 < IN; k0 += 32) {
    for (int id = tx; id < 512; id += 256) {
      int i = id >> 3, kk4 = (id & 7) * 4;
      int node = base + i;
      float4 v = make_float4(0.f, 0.f, 0.f, 0.f);
      if (node < n) v = *(const float4*)(X + (size_t)node * IN + k0 + kk4);
      *(float4*)(Xs + i * 32 + kk4) = v;
    }
    for (int id = tx; id < 1536; id += 256) {
      int kk = id / 48;
      int j = (id % 48) * 4;
      int half = (j >= 96) ? 1 : 0;
      int jj = j - half * 96;
      int e = jj >> 5, o = jj & 31;
      float4 v = *(const float4*)(eW + ((size_t)((e * 2 + half) * IN) + k0 + kk) * 32 + o);
      *(float4*)(Ws + kk * 192 + j) = v;
    }
    __syncthreads();
#pragma unroll 4
    for (int kk = 0; kk < 32; ++kk) {
      float xv[8], wv[6];
#pragma unroll
      for (int i = 0; i < 8; ++i) xv[i] = Xs[(nn0 + i) * 32 + kk];  // half-wave broadcast
#pragma unroll
      for (int c = 0; c < 6; ++c) wv[c] = Ws[kk * 192 + t32 + 32 * c];  // bank = t32, clean
#pragma unroll
      for (int i = 0; i < 8; ++i)
#pragma unroll
        for (int c = 0; c < 6; ++c) acc[i][c] = fmaf(xv[i], wv[c], acc[i][c]);
    }
    __syncthreads();
  }
#pragma unroll
  for (int i = 0; i < 8; ++i) {
    int node = base + nn0 + i;
    if (node < n) {
#pragma unroll
      for (int c = 0; c < 6; ++c) P[(size_t)node * 192 + t32 + 32 * c] = acc[i][c];
    }
  }
}

// ---------------- edge aggregation (gather over CSR) ----------------

__global__ __launch_bounds__(256) void aggregate_kernel(const float* __restrict__ P,
                                                        const int* __restrict__ rowstart,
                                                        const int* __restrict__ edata,
                                                        const float* __restrict__ eb,
                                                        float* __restrict__ h, int n) {
  int wid = (blockIdx.x * 256 + threadIdx.x) >> 6;
  if (wid >= n) return;
  int lane = threadIdx.x & 63;
  int o = lane & 31, slot = lane >> 5;
  const float* Pd = P + (size_t)wid * 192 + 96;
  float pdb0 = Pd[o] + eb[o];
  float pdb1 = Pd[32 + o] + eb[32 + o];
  float pdb2 = Pd[64 + o] + eb[64 + o];
  float a0 = 0.f, a1 = 0.f, a2 = 0.f;
  int c0 = 0, c1 = 0, c2 = 0;
  int s = rowstart[wid], e = rowstart[wid + 1];
  for (int i = s + slot; i < e; i += 2) {
    int pk = edata[i];  // broadcast within half-wave
    int srcn = pk & 0xFFFF;
    int et = pk >> 16;
    float v = P[(size_t)srcn * 192 + et * 32 + o];  // 128B coalesced per half-wave
    float pb = (et == 0) ? pdb0 : ((et == 1) ? pdb1 : pdb2);
    float m = fmaxf(v + pb, 0.f);
    a0 += (et == 0) ? m : 0.f;
    a1 += (et == 1) ? m : 0.f;
    a2 += (et == 2) ? m : 0.f;
    c0 += (et == 0);
    c1 += (et == 1);
    c2 += (et == 2);
  }
  a0 += __shfl_xor(a0, 32);
  a1 += __shfl_xor(a1, 32);
  a2 += __shfl_xor(a2, 32);
  c0 += __shfl_xor(c0, 32);
  c1 += __shfl_xor(c1, 32);
  c2 += __shfl_xor(c2, 32);
  if (slot == 0) {
    float* hn = h + (size_t)wid * 96;
    hn[o] = a0 / fmaxf((float)c0, 1.f);
    hn[32 + o] = a1 / fmaxf((float)c1, 1.f);
    hn[64 + o] = a2 / fmaxf((float)c2, 1.f);
  }
}

// ---------------- node MLP (type-partitioned): out[row] = relu(H[row] @ nW[t] + nb[t]) ----------------
// Blocks cover 64-node chunks of idx0 list, then idx1 list (counts read device-side).
// Tile: 64 nodes x OUT. Thread: 8 nodes (broadcast xv) x CO=OUT/32 outputs.
// Inner loop: per 4-kk group, 8 broadcast ds_read_b128 (Xs) + CO strided b128 (Ws, pitch 36).

template <int OUT>
__global__ __launch_bounds__(256) void mlp2_kernel(const float* __restrict__ H,
                                                   const float* __restrict__ nW,
                                                   const float* __restrict__ nb,
                                                   const int* __restrict__ idxbuf,
                                                   const int* __restrict__ tcnt,
                                                   float* __restrict__ out, int ncap) {
  constexpr int CO = OUT / 32;  // 4 (OUT=128) or 2 (OUT=64)
  constexpr int WP = 36;        // Ws pitch: breaks 32-stride bank aliasing
  __shared__ float Xs[64 * 32];    // [node][kk]   8 KB
  __shared__ float Ws[OUT * WP];   // [j][kk]      18.4 KB (OUT=128)

  int c0 = tcnt[0];
  int nb0 = (c0 + 63) >> 6;
  int t, base, cnt;
  if ((int)blockIdx.x < nb0) {
    t = 0; base = blockIdx.x << 6; cnt = c0;
  } else {
    t = 1; base = ((int)blockIdx.x - nb0) << 6; cnt = tcnt[1];
    if (base >= cnt) return;
  }
  const float* W = nW + (size_t)t * 96 * OUT;
  const float* bias = nb + t * OUT;
  const int* il = idxbuf + (size_t)t * ncap;

  const int tx = threadIdx.x;
  const int t32 = tx & 31;
  const int ng = tx >> 5;  // node group: 8 nodes each

  float acc[8][CO];
#pragma unroll
  for (int i = 0; i < 8; ++i)
#pragma unroll
    for (int c = 0; c < CO; ++c) acc[i][c] = 0.f;

  for (int k0 = 0; k0 < 96; k0 += 32) {
    // stage X: gathered rows, [node][kk], pitch 32 (writes & broadcast reads conflict-free)
    for (int id = tx; id < 512; id += 256) {
      int i = id >> 3, kk4 = (id & 7) * 4;
      float4 v = make_float4(0.f, 0.f, 0.f, 0.f);
      if (base + i < cnt) {
        int row = il[base + i];
        v = *(const float4*)(H + (size_t)row * 96 + k0 + kk4);
      }
      *(float4*)(Xs + i * 32 + kk4) = v;
    }
    // stage W transposed: [j][kk] pitch 36; global read coalesced over j
    for (int id = tx; id < 32 * (OUT / 4); id += 256) {
      int kk = id / (OUT / 4);
      int j4 = (id % (OUT / 4)) * 4;
      float4 v = *(const float4*)(W + (size_t)(k0 + kk) * OUT + j4);
      Ws[(j4 + 0) * WP + kk] = v.x;
      Ws[(j4 + 1) * WP + kk] = v.y;
      Ws[(j4 + 2) * WP + kk] = v.z;
      Ws[(j4 + 3) * WP + kk] = v.w;
    }
    __syncthreads();
#pragma unroll
    for (int g = 0; g < 8; ++g) {  // kk4 = 4*g
      float4 xv[8], wv[CO];
#pragma unroll
      for (int i = 0; i < 8; ++i) xv[i] = *(const float4*)(Xs + (ng * 8 + i) * 32 + 4 * g);
#pragma unroll
      for (int c = 0; c < CO; ++c) wv[c] = *(const float4*)(Ws + (t32 + 32 * c) * WP + 4 * g);
#pragma unroll
      for (int i = 0; i < 8; ++i)
#pragma unroll
        for (int c = 0; c < CO; ++c) {
          acc[i][c] = fmaf(xv[i].x, wv[c].x, acc[i][c]);
          acc[i][c] = fmaf(xv[i].y, wv[c].y, acc[i][c]);
          acc[i][c] = fmaf(xv[i].z, wv[c].z, acc[i][c]);
          acc[i][c] = fmaf(xv[i].w, wv[c].w, acc[i][c]);
        }
    }
    __syncthreads();
  }

  float bj[CO];
#pragma unroll
  for (int c = 0; c < CO; ++c) bj[c] = bias[t32 + 32 * c];
#pragma unroll
  for (int i = 0; i < 8; ++i) {
    int slot = base + ng * 8 + i;
    if (slot < cnt) {
      int row = il[slot];
#pragma unroll
      for (int c = 0; c < CO; ++c)
        out[(size_t)row * OUT + t32 + 32 * c] = fmaxf(acc[i][c] + bj[c], 0.f);
    }
  }
}

// ---------------- launch ----------------

extern "C" void kernel_launch(void* const* d_in, const int* in_sizes, int n_in,
                              void* d_out, int out_size, void* d_ws, size_t ws_size,
                              hipStream_t stream) {
  const float* nf    = (const float*)d_in[0];
  const int*   eidx  = (const int*)d_in[1];
  const int*   etype = (const int*)d_in[2];
  const int*   ntype = (const int*)d_in[3];
  const float* eW0   = (const float*)d_in[4];
  const float* eb0   = (const float*)d_in[5];
  const float* nW0   = (const float*)d_in[6];
  const float* nb0   = (const float*)d_in[7];
  const float* eW1   = (const float*)d_in[8];
  const float* eb1   = (const float*)d_in[9];
  const float* nW1   = (const float*)d_in[10];
  const float* nb1   = (const float*)d_in[11];
  const int N = in_sizes[3];   // node_type count
  const int E = in_sizes[2];   // edge_type count
  const int* srcv = eidx;
  const int* dstv = eidx + E;

  // workspace layout (~75 MB)
  float* P   = (float*)d_ws;                 // N*192
  float* h96 = P + (size_t)N * 192;          // N*96
  float* h64 = h96 + (size_t)N * 96;         // N*64
  int* rowstart = (int*)(h64 + (size_t)N * 64);  // N+1 (padded to N+4)
  int* cursor   = rowstart + ((N + 4) & ~3);     // N   (16B-aligned for int4)
  int* tcnt     = cursor + N;                    // 2   (zeroed with cursor)
  int* bsum     = tcnt + 2;                      // 64
  int* boff     = bsum + 64;                     // 64
  int* idxbuf   = boff + 64;                     // 2*N
  int* edata    = idxbuf + 2 * N;                // E

  const int nsb = (N + 1023) / 1024;  // scan blocks (<=64 for N<=65536)

  // CSR build + node partition (graph identical for both layers)
  hipMemsetAsync(cursor, 0, (size_t)(N + 2) * sizeof(int), stream);
  count_kernel<<<(E + 255) / 256, 256, 0, stream>>>(dstv, cursor, E);
  scan1_kernel<<<nsb, 256, 0, stream>>>(cursor, rowstart, bsum, N);
  scan2_kernel<<<1, 64, 0, stream>>>(bsum, boff, nsb, rowstart, N);
  scan3_kernel<<<(N + 255) / 256, 256, 0, stream>>>(rowstart, cursor, boff, N);
  fill_kernel<<<(E + 255) / 256, 256, 0, stream>>>(srcv, dstv, etype, cursor, edata, E);
  partition_kernel<<<(N + 255) / 256, 256, 0, stream>>>(ntype, idxbuf, tcnt, N, N);

  int pgrid = (N + 63) / 64;
  int agrid = (N + 3) / 4;
  int mgrid = (N + 63) / 64 + 2;  // covers ceil(c0/64)+ceil(c1/64)

  // layer 0: 128 -> 64
  proj_kernel<128><<<pgrid, 256, 0, stream>>>(nf, eW0, P, N);
  aggregate_kernel<<<agrid, 256, 0, stream>>>(P, rowstart, edata, eb0, h96, N);
  mlp2_kernel<64><<<mgrid, 256, 0, stream>>>(h96, nW0, nb0, idxbuf, tcnt, h64, N);

  // layer 1: 64 -> 128
  proj_kernel<64><<<pgrid, 256, 0, stream>>>(h64, eW1, P, N);
  aggregate_kernel<<<agrid, 256, 0, stream>>>(P, rowstart, edata, eb1, h96, N);
  mlp2_kernel<128><<<mgrid, 256, 0, stream>>>(h96, nW1, nb1, idxbuf, tcnt, (float*)d_out, N);
}